// Round 8
// baseline (152.804 us; speedup 1.0000x reference)
//
#include <hip/hip_runtime.h>

// ConnectLoss fused kernel v10 for MI355X (gfx950).
//
// v9 post-mortem: XOR-select + split-accumulator = noise (main is
// latency-bound, not VALU-issue-bound); total 128.7 ~= v5's 128.1.
// Budget: 2 harness fills ~83 us (untouchable) + main ~35 + final ~4 +
// gaps ~6. v10 removes the second launch: last-block-done fused final
// (rocPRIM pattern). Each block: write 6 partials -> syncthreads -> tid0
// threadfence + atomicAdd(done); the block seeing old==NBLK-1 re-fences and
// runs the IDENTICAL final-reduction code (bit-identical FP order) with its
// 256 threads. 'done' counter in d_ws past partials, zeroed by a 4-byte
// hipMemsetAsync (graph-capture-safe; precedent in mode-0 path).
// Main kernel math/geometry unchanged from v9 (absmax 0.0).

#define HDIM 512
#define WDIM 512
#define HW (HDIM * WDIM)
#define BATCH 8
#define ROWS_PER_BLOCK 4
#define NBLKX (HDIM / ROWS_PER_BLOCK)   // 128 blocks per batch image
#define NBLK  (NBLKX * BATCH)           // 1024 blocks total

__device__ __forceinline__ float fast_sig(float x) {
    float e = __expf(-fabsf(x));
    float r = __builtin_amdgcn_rcpf(1.0f + e);
    return (x >= 0.0f) ? r : e * r;
}
// sigmoid(x); sp_out = log(1+exp(-|x|)) so softplus(+-x) = max(+-x,0) + sp_out
__device__ __forceinline__ float sig_sp(float x, float& sp_out) {
    float e = __expf(-fabsf(x));
    float d = 1.0f + e;
    sp_out = __logf(d);
    float r = __builtin_amdgcn_rcpf(d);
    return (x >= 0.0f) ? r : e * r;
}

struct Arr10 { float v[10]; };  // cols j0-1 .. j0+8 (halos via wave shuffle)

__device__ __forceinline__ void load8(const float* p, float* o) {
    const float4 a = *(const float4*)p;
    const float4 b = *(const float4*)(p + 4);
    o[0]=a.x; o[1]=a.y; o[2]=a.z; o[3]=a.w;
    o[4]=b.x; o[5]=b.y; o[6]=b.z; o[7]=b.w;
}

__device__ __forceinline__ void zero8(float* o) {
#pragma unroll
    for (int k = 0; k < 8; ++k) o[k] = 0.f;
}

__device__ __forceinline__ Arr10 strip10_from(const float* x, int lane) {
    Arr10 r;
    float l = __shfl_up(x[7], 1, 64);
    float h = __shfl_down(x[0], 1, 64);
    r.v[0] = (lane == 0)  ? 0.f : l;    // image-left boundary
    r.v[9] = (lane == 63) ? 0.f : h;    // image-right boundary
#pragma unroll
    for (int k = 0; k < 8; ++k) r.v[k + 1] = x[k];
    return r;
}

__global__ __launch_bounds__(256) void connect_loss_main(
        const float* __restrict__ pred,   // (B, 8, H, W)
        const float* __restrict__ tgt,    // (B, 1, H, W)
        float* __restrict__ partials,     // mode 1: [6][NBLK]
        double* __restrict__ wsd,         // mode 0: 27 doubles
        unsigned int* __restrict__ done,  // mode 1: block-done counter
        float* __restrict__ out,          // mode 1: final scalar output
        int mode)
{
    const int b    = blockIdx.y;
    const int tid  = threadIdx.x;
    const int lane = tid & 63;
    const int wv   = tid >> 6;
    const int i    = blockIdx.x * ROWS_PER_BLOCK + wv;  // wave == one row
    const int j0   = lane << 3;
    const int p0   = i * WDIM + j0;
    const bool rm  = (i > 0), rp = (i < HDIM - 1);
    const bool l0  = (lane == 0), l63 = (lane == 63);

    const float* tb = tgt  + (size_t)b * HW;
    const float* pb = pred + (size_t)b * 8 * HW;

    // ---------- issue ALL early loads first: target rows + sections 0,1 ----
    // Section s pairs channels (s, 7-s). Ra = ch(7-s) @ row i-1 (for vote of
    // d_s); Rb = ch(s) @ row i+1 (for vote of d_{7-s}).
    float t0[8], t1[8], t2[8];
    zero8(t0); zero8(t2);
    if (rm) load8(tb + p0 - WDIM, t0);
    load8(tb + p0, t1);
    if (rp) load8(tb + p0 + WDIM, t2);

    float Axa[8], Axb[8], Ara[8], Arb[8];
    float Bxa[8], Bxb[8], Bra[8], Brb[8];

    auto pload = [&](int cA, int cB, float* Xa, float* Xb, float* Ra, float* Rb) {
        load8(pb + (size_t)cA * HW + p0, Xa);
        load8(pb + (size_t)cB * HW + p0, Xb);
        if (rm) load8(pb + (size_t)cB * HW + p0 - WDIM, Ra); else zero8(Ra);
        if (rp) load8(pb + (size_t)cA * HW + p0 + WDIM, Rb); else zero8(Rb);
    };
    pload(0, 7, Axa, Axb, Ara, Arb);        // section 0
    pload(1, 6, Bxa, Bxb, Bra, Brb);        // section 1 (prefetch)

    // ---------- target strips + conn/edge bits (covers pred load latency) --
    Arr10 tm = strip10_from(t0, lane);
    Arr10 tc = strip10_from(t1, lane);
    Arr10 tp = strip10_from(t2, lane);

    int mb[8];
#pragma unroll
    for (int k = 0; k < 8; ++k) {
        const float t_ = tc.v[k + 1];
        const float s8 = tm.v[k] + tm.v[k+1] + tm.v[k+2]
                       + tc.v[k] + tc.v[k+2]
                       + tp.v[k] + tp.v[k+1] + tp.v[k+2];
        const float sc = t_ * s8;
        int bits = (sc < 8.0f && sc > 0.0f) ? 256 : 0;
        if (t_ > 0.5f) {
            bits |= (tm.v[k]   > 0.5f ?   1 : 0);
            bits |= (tm.v[k+1] > 0.5f ?   2 : 0);
            bits |= (tm.v[k+2] > 0.5f ?   4 : 0);
            bits |= (tc.v[k]   > 0.5f ?   8 : 0);
            bits |= (tc.v[k+2] > 0.5f ?  16 : 0);
            bits |= (tp.v[k]   > 0.5f ?  32 : 0);
            bits |= (tp.v[k+1] > 0.5f ?  64 : 0);
            bits |= (tp.v[k+2] > 0.5f ? 128 : 0);
        }
        mb[k] = bits;
    }

    float fp[8], xmin[8], bce0 = 0.f, bce1 = 0.f;
#pragma unroll
    for (int k = 0; k < 8; ++k) { fp[k] = 0.f; xmin[k] = 1e30f; }

    // own-channel math: sigmoid + BCE (logit-space softplus, XOR-sign select)
    auto own_ch = [&](int c, const float* x, float* s, float& acc) {
#pragma unroll
        for (int k = 0; k < 8; ++k) {
            float sp;
            const float sv = sig_sp(x[k], sp);
            s[k] = sv;
            xmin[k] = fminf(xmin[k], x[k]);
            const int sbit = (mb[k] << (31 - c)) & 0x80000000;
            const float sel = __int_as_float(__float_as_int(x[k]) ^ sbit);
            acc += fminf(fmaxf(sel, 0.f) + sp, 100.f);
        }
    };
    // vote: fp[k] = max(fp[k], s[k] * sigmoid(neigh)); off 0/1/2 = col -1/0/+1
    auto vote = [&](const float* s, const Arr10& n, int off, bool rv) {
#pragma unroll
        for (int k = 0; k < 8; ++k) {
            bool ok = rv;
            if (off == 0 && k == 0) ok = ok && !l0;
            if (off == 2 && k == 7) ok = ok && !l63;
            const float q = ok ? fast_sig(n.v[k + off]) : 0.f;
            fp[k] = fmaxf(fp[k], s[k] * q);
        }
    };
    auto section = [&](int cA, int cB, const float* Xa, const float* Xb,
                       const float* Ra, const float* Rb,
                       int offA, int offB, bool gA, bool gB) {
        Arr10 nA = strip10_from(Ra, lane);
        Arr10 nB = strip10_from(Rb, lane);
        float s_a[8], s_b[8];
        own_ch(cA, Xa, s_a, bce0);
        own_ch(cB, Xb, s_b, bce1);
        vote(s_a, nA, offA, gA);
        vote(s_b, nB, offB, gB);
    };

    // ---------- pipelined sections: compute s while s+1 loads are in flight
    section(0, 7, Axa, Axb, Ara, Arb, 0, 2, rm, rp);
    pload(2, 5, Axa, Axb, Ara, Arb);        // section 2 (prefetch into A)
    section(1, 6, Bxa, Bxb, Bra, Brb, 1, 1, rm, rp);
    load8(pb + 3 * (size_t)HW + p0, Bxa);   // section 3: in-row pair (3,4)
    load8(pb + 4 * (size_t)HW + p0, Bxb);
    section(2, 5, Axa, Axb, Ara, Arb, 2, 0, rm, rp);
    section(3, 4, Bxa, Bxb, Bxb, Bxa, 0, 2, true, true);

    // ---------- epilogue: edge loss + dice partials ----------
    float e_num = 0.f, e_den = 0.f, inter = 0.f, fpsum = 0.f, tsum = 0.f;
#pragma unroll
    for (int k = 0; k < 8; ++k) {
        const float ef = (mb[k] & 256) ? 1.f : 0.f;
        const float m  = xmin[k];
        const float t_ = tc.v[k + 1];
        float sp;
        const float pmin = sig_sp(m, sp);           // sigmoid monotone
        e_num += ef * fminf(fmaxf(m, 0.f) + sp, 100.f);  // softplus(xmin)
        e_den += ef * pmin;
        inter += fp[k] * t_;
        fpsum += fp[k];
        tsum  += t_;
    }

    // ---------- block reduction of 6 partials ----------
    float vals[6] = {bce0 + bce1, e_num, e_den, inter, fpsum, tsum};
    __shared__ float red[4][6];
#pragma unroll
    for (int k = 0; k < 6; ++k) {
        float v = vals[k];
#pragma unroll
        for (int o = 32; o > 0; o >>= 1) v += __shfl_down(v, o, 64);
        if (lane == 0) red[wv][k] = v;
    }
    __syncthreads();
    if (tid < 6) {
        const int k = tid;
        const float sum = red[0][k] + red[1][k] + red[2][k] + red[3][k];
        if (mode == 1) {
            partials[k * NBLK + b * NBLKX + blockIdx.x] = sum;
        } else {
            double* dst;
            switch (k) {
                case 0:  dst = wsd + 0;       break;
                case 1:  dst = wsd + 1;       break;
                case 2:  dst = wsd + 2;       break;
                case 3:  dst = wsd + 3 + b;   break;
                case 4:  dst = wsd + 11 + b;  break;
                default: dst = wsd + 19 + b;  break;
            }
            atomicAdd(dst, (double)sum);
        }
    }

    // ---------- fused final: last block reduces partials -> out ----------
    if (mode == 1) {
        __shared__ int isLastSh;
        __syncthreads();                  // all 6 partials stores complete
        if (tid == 0) {
            __threadfence();              // publish partials device-wide
            isLastSh = (atomicAdd(done, 1u) == (unsigned)(NBLK - 1));
        }
        __syncthreads();
        if (isLastSh) {                   // block-uniform
            __threadfence();              // acquire: all blocks' partials
            __shared__ double red4[4];
            __shared__ double gsum[3];
            __shared__ double bsum[3][BATCH];
            const int t = tid;
            const int fl = t & 63, wid = t >> 6;
            {   // per-batch categories (k=3,4,5): 8 groups of 32 lanes
                const int g = t >> 5, e = t & 31;
#pragma unroll
                for (int k = 3; k < 6; ++k) {
                    double v = 0.0;
                    for (int m = e; m < NBLKX; m += 32)
                        v += (double)partials[k * NBLK + g * NBLKX + m];
                    for (int o = 16; o > 0; o >>= 1) v += __shfl_down(v, o, 32);
                    if (e == 0) bsum[k - 3][g] = v;
                }
            }
            for (int k = 0; k < 3; ++k) {   // global categories
                double v = 0.0;
                for (int idx = t; idx < NBLK; idx += 256)
                    v += (double)partials[k * NBLK + idx];
                for (int o = 32; o > 0; o >>= 1) v += __shfl_down(v, o, 64);
                if (fl == 0) red4[wid] = v;
                __syncthreads();
                if (t == 0) gsum[k] = red4[0] + red4[1] + red4[2] + red4[3];
                __syncthreads();
            }
            if (t == 0) {
                const double conn_loss = gsum[0] / (double)((size_t)BATCH * 8 * HW);
                const double edge_loss = gsum[1] / gsum[2];
                double seg = 0.0;
                for (int bb = 0; bb < BATCH; ++bb) {
                    const double dice = (2.0 * bsum[0][bb] + 1.0)
                                      / (bsum[1][bb] + bsum[2][bb] + 1.0);
                    seg += 1.0 - dice;
                }
                out[0] = (float)(conn_loss + edge_loss + seg / (double)BATCH);
            }
        }
    }
}

// mode-0 fallback only (ws too small for partials): tiny scalar finish
__global__ __launch_bounds__(64) void connect_loss_final0(
        const double* __restrict__ wsd, float* __restrict__ out)
{
    if (threadIdx.x == 0) {
        const double conn_loss = wsd[0] / (double)((size_t)BATCH * 8 * HW);
        const double edge_loss = wsd[1] / wsd[2];
        double seg = 0.0;
        for (int bb = 0; bb < BATCH; ++bb) {
            const double dice = (2.0 * wsd[3 + bb] + 1.0)
                              / (wsd[11 + bb] + wsd[19 + bb] + 1.0);
            seg += 1.0 - dice;
        }
        out[0] = (float)(conn_loss + edge_loss + seg / (double)BATCH);
    }
}

extern "C" void kernel_launch(void* const* d_in, const int* in_sizes, int n_in,
                              void* d_out, int out_size, void* d_ws, size_t ws_size,
                              hipStream_t stream)
{
    const float* pred = (const float*)d_in[0];   // (8, 8, 512, 512)
    const float* tgt  = (const float*)d_in[1];   // (8, 1, 512, 512)
    // d_in[2]/d_in[3] (hori/verti) are exact one-pixel shift permutation
    // matrices -> implemented as index shifts (verified earlier, absmax 0).

    const dim3 grid(NBLKX, BATCH);
    const size_t partBytes = (size_t)6 * NBLK * sizeof(float);
    const size_t needA = partBytes + sizeof(unsigned int);

    if (ws_size >= needA) {
        float* partials = (float*)d_ws;
        unsigned int* done = (unsigned int*)((char*)d_ws + partBytes);
        hipMemsetAsync(done, 0, sizeof(unsigned int), stream);
        connect_loss_main<<<grid, 256, 0, stream>>>(
            pred, tgt, partials, nullptr, done, (float*)d_out, 1);
    } else {
        double* wsd = (double*)d_ws;
        hipMemsetAsync(d_ws, 0, 27 * sizeof(double), stream);
        connect_loss_main<<<grid, 256, 0, stream>>>(
            pred, tgt, nullptr, wsd, nullptr, (float*)d_out, 0);
        connect_loss_final0<<<1, 64, 0, stream>>>(wsd, (float*)d_out);
    }
}

// Round 9
// 150.893 us; speedup vs baseline: 1.0127x; 1.0127x over previous
//
#include <hip/hip_runtime.h>

// ConnectLoss fused kernel v11 for MI355X (gfx950).
//
// v10 post-mortem: last-block-done fusion regressed main 35->61 us — 1024
// device-scope threadfences + same-cacheline atomics serialize cross-XCD,
// costing far more than the launch it saved. Reverted: two-kernel structure
// stands (lesson: grid-wide done-counters are anti-optimizations on 8-XCD
// MI355X).
// v11 = v9's verified main (128.7 us total, absmax 0.0, latency-bound at
// VALU 48%/HBM 14%; five structural attacks all regressed -> locally
// converged) + single-WAVE final kernel: 64 lanes, lane-strided coalesced
// loads, butterfly shfl reductions, no barriers, no LDS (was: 256 thr,
// 4 syncthreads, LDS staging). Double-accumulator order changes are absorbed
// by double->float rounding (demonstrated absmax 0.0 across v4/v9 layout
// changes).

#define HDIM 512
#define WDIM 512
#define HW (HDIM * WDIM)
#define BATCH 8
#define ROWS_PER_BLOCK 4
#define NBLKX (HDIM / ROWS_PER_BLOCK)   // 128 blocks per batch image
#define NBLK  (NBLKX * BATCH)           // 1024 blocks total

__device__ __forceinline__ float fast_sig(float x) {
    float e = __expf(-fabsf(x));
    float r = __builtin_amdgcn_rcpf(1.0f + e);
    return (x >= 0.0f) ? r : e * r;
}
// sigmoid(x); sp_out = log(1+exp(-|x|)) so softplus(+-x) = max(+-x,0) + sp_out
__device__ __forceinline__ float sig_sp(float x, float& sp_out) {
    float e = __expf(-fabsf(x));
    float d = 1.0f + e;
    sp_out = __logf(d);
    float r = __builtin_amdgcn_rcpf(d);
    return (x >= 0.0f) ? r : e * r;
}

struct Arr10 { float v[10]; };  // cols j0-1 .. j0+8 (halos via wave shuffle)

__device__ __forceinline__ void load8(const float* p, float* o) {
    const float4 a = *(const float4*)p;
    const float4 b = *(const float4*)(p + 4);
    o[0]=a.x; o[1]=a.y; o[2]=a.z; o[3]=a.w;
    o[4]=b.x; o[5]=b.y; o[6]=b.z; o[7]=b.w;
}

__device__ __forceinline__ void zero8(float* o) {
#pragma unroll
    for (int k = 0; k < 8; ++k) o[k] = 0.f;
}

__device__ __forceinline__ Arr10 strip10_from(const float* x, int lane) {
    Arr10 r;
    float l = __shfl_up(x[7], 1, 64);
    float h = __shfl_down(x[0], 1, 64);
    r.v[0] = (lane == 0)  ? 0.f : l;    // image-left boundary
    r.v[9] = (lane == 63) ? 0.f : h;    // image-right boundary
#pragma unroll
    for (int k = 0; k < 8; ++k) r.v[k + 1] = x[k];
    return r;
}

__global__ __launch_bounds__(256) void connect_loss_main(
        const float* __restrict__ pred,   // (B, 8, H, W)
        const float* __restrict__ tgt,    // (B, 1, H, W)
        float* __restrict__ partials,     // mode 1: [6][NBLK]
        double* __restrict__ wsd,         // mode 0: 27 doubles
        int mode)
{
    const int b    = blockIdx.y;
    const int tid  = threadIdx.x;
    const int lane = tid & 63;
    const int wv   = tid >> 6;
    const int i    = blockIdx.x * ROWS_PER_BLOCK + wv;  // wave == one row
    const int j0   = lane << 3;
    const int p0   = i * WDIM + j0;
    const bool rm  = (i > 0), rp = (i < HDIM - 1);
    const bool l0  = (lane == 0), l63 = (lane == 63);

    const float* tb = tgt  + (size_t)b * HW;
    const float* pb = pred + (size_t)b * 8 * HW;

    // ---------- issue ALL early loads first: target rows + sections 0,1 ----
    // Section s pairs channels (s, 7-s). Ra = ch(7-s) @ row i-1 (for vote of
    // d_s); Rb = ch(s) @ row i+1 (for vote of d_{7-s}).
    float t0[8], t1[8], t2[8];
    zero8(t0); zero8(t2);
    if (rm) load8(tb + p0 - WDIM, t0);
    load8(tb + p0, t1);
    if (rp) load8(tb + p0 + WDIM, t2);

    float Axa[8], Axb[8], Ara[8], Arb[8];
    float Bxa[8], Bxb[8], Bra[8], Brb[8];

    auto pload = [&](int cA, int cB, float* Xa, float* Xb, float* Ra, float* Rb) {
        load8(pb + (size_t)cA * HW + p0, Xa);
        load8(pb + (size_t)cB * HW + p0, Xb);
        if (rm) load8(pb + (size_t)cB * HW + p0 - WDIM, Ra); else zero8(Ra);
        if (rp) load8(pb + (size_t)cA * HW + p0 + WDIM, Rb); else zero8(Rb);
    };
    pload(0, 7, Axa, Axb, Ara, Arb);        // section 0
    pload(1, 6, Bxa, Bxb, Bra, Brb);        // section 1 (prefetch)

    // ---------- target strips + conn/edge bits (covers pred load latency) --
    Arr10 tm = strip10_from(t0, lane);
    Arr10 tc = strip10_from(t1, lane);
    Arr10 tp = strip10_from(t2, lane);

    int mb[8];
#pragma unroll
    for (int k = 0; k < 8; ++k) {
        const float t_ = tc.v[k + 1];
        const float s8 = tm.v[k] + tm.v[k+1] + tm.v[k+2]
                       + tc.v[k] + tc.v[k+2]
                       + tp.v[k] + tp.v[k+1] + tp.v[k+2];
        const float sc = t_ * s8;
        int bits = (sc < 8.0f && sc > 0.0f) ? 256 : 0;
        if (t_ > 0.5f) {
            bits |= (tm.v[k]   > 0.5f ?   1 : 0);
            bits |= (tm.v[k+1] > 0.5f ?   2 : 0);
            bits |= (tm.v[k+2] > 0.5f ?   4 : 0);
            bits |= (tc.v[k]   > 0.5f ?   8 : 0);
            bits |= (tc.v[k+2] > 0.5f ?  16 : 0);
            bits |= (tp.v[k]   > 0.5f ?  32 : 0);
            bits |= (tp.v[k+1] > 0.5f ?  64 : 0);
            bits |= (tp.v[k+2] > 0.5f ? 128 : 0);
        }
        mb[k] = bits;
    }

    float fp[8], xmin[8], bce0 = 0.f, bce1 = 0.f;
#pragma unroll
    for (int k = 0; k < 8; ++k) { fp[k] = 0.f; xmin[k] = 1e30f; }

    // own-channel math: sigmoid + BCE (logit-space softplus, XOR-sign select)
    // bit c of mb[k] set -> target=1 -> loss = softplus(-x); else softplus(x).
    auto own_ch = [&](int c, const float* x, float* s, float& acc) {
#pragma unroll
        for (int k = 0; k < 8; ++k) {
            float sp;
            const float sv = sig_sp(x[k], sp);
            s[k] = sv;
            xmin[k] = fminf(xmin[k], x[k]);
            const int sbit = (mb[k] << (31 - c)) & 0x80000000;
            const float sel = __int_as_float(__float_as_int(x[k]) ^ sbit);
            acc += fminf(fmaxf(sel, 0.f) + sp, 100.f);
        }
    };
    // vote: fp[k] = max(fp[k], s[k] * sigmoid(neigh)); off 0/1/2 = col -1/0/+1
    auto vote = [&](const float* s, const Arr10& n, int off, bool rv) {
#pragma unroll
        for (int k = 0; k < 8; ++k) {
            bool ok = rv;
            if (off == 0 && k == 0) ok = ok && !l0;
            if (off == 2 && k == 7) ok = ok && !l63;
            const float q = ok ? fast_sig(n.v[k + off]) : 0.f;
            fp[k] = fmaxf(fp[k], s[k] * q);
        }
    };
    auto section = [&](int cA, int cB, const float* Xa, const float* Xb,
                       const float* Ra, const float* Rb,
                       int offA, int offB, bool gA, bool gB) {
        Arr10 nA = strip10_from(Ra, lane);
        Arr10 nB = strip10_from(Rb, lane);
        float s_a[8], s_b[8];
        own_ch(cA, Xa, s_a, bce0);
        own_ch(cB, Xb, s_b, bce1);
        vote(s_a, nA, offA, gA);
        vote(s_b, nB, offB, gB);
    };

    // ---------- pipelined sections: compute s while s+1 loads are in flight
    section(0, 7, Axa, Axb, Ara, Arb, 0, 2, rm, rp);
    pload(2, 5, Axa, Axb, Ara, Arb);        // section 2 (prefetch into A)
    section(1, 6, Bxa, Bxb, Bra, Brb, 1, 1, rm, rp);
    load8(pb + 3 * (size_t)HW + p0, Bxa);   // section 3: in-row pair (3,4)
    load8(pb + 4 * (size_t)HW + p0, Bxb);
    section(2, 5, Axa, Axb, Ara, Arb, 2, 0, rm, rp);
    section(3, 4, Bxa, Bxb, Bxb, Bxa, 0, 2, true, true);

    // ---------- epilogue: edge loss + dice partials ----------
    float e_num = 0.f, e_den = 0.f, inter = 0.f, fpsum = 0.f, tsum = 0.f;
#pragma unroll
    for (int k = 0; k < 8; ++k) {
        const float ef = (mb[k] & 256) ? 1.f : 0.f;
        const float m  = xmin[k];
        const float t_ = tc.v[k + 1];
        float sp;
        const float pmin = sig_sp(m, sp);           // sigmoid monotone
        e_num += ef * fminf(fmaxf(m, 0.f) + sp, 100.f);  // softplus(xmin)
        e_den += ef * pmin;
        inter += fp[k] * t_;
        fpsum += fp[k];
        tsum  += t_;
    }

    // ---------- block reduction of 6 partials ----------
    float vals[6] = {bce0 + bce1, e_num, e_den, inter, fpsum, tsum};
    __shared__ float red[4][6];
#pragma unroll
    for (int k = 0; k < 6; ++k) {
        float v = vals[k];
#pragma unroll
        for (int o = 32; o > 0; o >>= 1) v += __shfl_down(v, o, 64);
        if (lane == 0) red[wv][k] = v;
    }
    __syncthreads();
    if (tid < 6) {
        const int k = tid;
        const float sum = red[0][k] + red[1][k] + red[2][k] + red[3][k];
        if (mode == 1) {
            partials[k * NBLK + b * NBLKX + blockIdx.x] = sum;
        } else {
            double* dst;
            switch (k) {
                case 0:  dst = wsd + 0;       break;
                case 1:  dst = wsd + 1;       break;
                case 2:  dst = wsd + 2;       break;
                case 3:  dst = wsd + 3 + b;   break;
                case 4:  dst = wsd + 11 + b;  break;
                default: dst = wsd + 19 + b;  break;
            }
            atomicAdd(dst, (double)sum);
        }
    }
}

// single-wave final: 64 lanes, coalesced strided loads, butterfly shfl
// reductions, no barriers, no LDS.
__global__ __launch_bounds__(64) void connect_loss_final(
        const float* __restrict__ partials,
        const double* __restrict__ wsd,
        float* __restrict__ out, int mode)
{
    const int lane = threadIdx.x;
    if (mode == 1) {
        double g[3];
#pragma unroll
        for (int k = 0; k < 3; ++k) {           // global categories
            double v = 0.0;
            for (int idx = lane; idx < NBLK; idx += 64)
                v += (double)partials[k * NBLK + idx];
#pragma unroll
            for (int o = 32; o > 0; o >>= 1) v += __shfl_down(v, o, 64);
            g[k] = v;                           // valid on lane 0
        }
        double bs[3][BATCH];
#pragma unroll
        for (int k = 3; k < 6; ++k) {           // per-batch categories
#pragma unroll
            for (int bb = 0; bb < BATCH; ++bb) {
                double v = 0.0;
                for (int m = lane; m < NBLKX; m += 64)
                    v += (double)partials[k * NBLK + bb * NBLKX + m];
#pragma unroll
                for (int o = 32; o > 0; o >>= 1) v += __shfl_down(v, o, 64);
                bs[k - 3][bb] = v;              // valid on lane 0
            }
        }
        if (lane == 0) {
            const double conn_loss = g[0] / (double)((size_t)BATCH * 8 * HW);
            const double edge_loss = g[1] / g[2];
            double seg = 0.0;
#pragma unroll
            for (int bb = 0; bb < BATCH; ++bb) {
                const double dice = (2.0 * bs[0][bb] + 1.0)
                                  / (bs[1][bb] + bs[2][bb] + 1.0);
                seg += 1.0 - dice;
            }
            out[0] = (float)(conn_loss + edge_loss + seg / (double)BATCH);
        }
    } else if (lane == 0) {
        const double conn_loss = wsd[0] / (double)((size_t)BATCH * 8 * HW);
        const double edge_loss = wsd[1] / wsd[2];
        double seg = 0.0;
#pragma unroll
        for (int bb = 0; bb < BATCH; ++bb) {
            const double dice = (2.0 * wsd[3 + bb] + 1.0)
                              / (wsd[11 + bb] + wsd[19 + bb] + 1.0);
            seg += 1.0 - dice;
        }
        out[0] = (float)(conn_loss + edge_loss + seg / (double)BATCH);
    }
}

extern "C" void kernel_launch(void* const* d_in, const int* in_sizes, int n_in,
                              void* d_out, int out_size, void* d_ws, size_t ws_size,
                              hipStream_t stream)
{
    const float* pred = (const float*)d_in[0];   // (8, 8, 512, 512)
    const float* tgt  = (const float*)d_in[1];   // (8, 1, 512, 512)
    // d_in[2]/d_in[3] (hori/verti) are exact one-pixel shift permutation
    // matrices -> implemented as index shifts (verified earlier, absmax 0).

    const dim3 grid(NBLKX, BATCH);
    const size_t needA = (size_t)6 * NBLK * sizeof(float);

    if (ws_size >= needA) {
        float* partials = (float*)d_ws;
        connect_loss_main<<<grid, 256, 0, stream>>>(pred, tgt, partials, nullptr, 1);
        connect_loss_final<<<1, 64, 0, stream>>>(partials, nullptr, (float*)d_out, 1);
    } else {
        double* wsd = (double*)d_ws;
        hipMemsetAsync(d_ws, 0, 27 * sizeof(double), stream);
        connect_loss_main<<<grid, 256, 0, stream>>>(pred, tgt, nullptr, wsd, 0);
        connect_loss_final<<<1, 64, 0, stream>>>(nullptr, wsd, (float*)d_out, 0);
    }
}

// Round 10
// 130.167 us; speedup vs baseline: 1.1739x; 1.1592x over previous
//
#include <hip/hip_runtime.h>

// ConnectLoss fused kernel v12 for MI355X (gfx950).
//
// v11 post-mortem: single-wave final regressed total 128.7 -> 150.9. The
// 256-thread final's cost was memory LATENCY (hidden by its 4 waves), not
// barriers/LDS; one wave exposed ~27 serial load-reduce round trips (~20 us).
// Lesson (pairs with v10's): for tiny reductions, latency-hiding parallelism
// beats barrier elimination.
// v12 = exact revert to v9 (best verified config of the session, 128.7 us,
// absmax 0.0): v5's depth-1 pipelined main (1 row/wave, 1024 blocks,
// [6][1024] partials) + XOR-sign BCE select + split bce accumulator +
// original 256-thread final. Session floor accounting: harness fills ~83 us
// (untouchable) + main ~35 (latency-bound; six structural attacks regressed)
// + final ~4.5 + gaps ~5 = ~127.5.

#define HDIM 512
#define WDIM 512
#define HW (HDIM * WDIM)
#define BATCH 8
#define ROWS_PER_BLOCK 4
#define NBLKX (HDIM / ROWS_PER_BLOCK)   // 128 blocks per batch image
#define NBLK  (NBLKX * BATCH)           // 1024 blocks total

__device__ __forceinline__ float fast_sig(float x) {
    float e = __expf(-fabsf(x));
    float r = __builtin_amdgcn_rcpf(1.0f + e);
    return (x >= 0.0f) ? r : e * r;
}
// sigmoid(x); sp_out = log(1+exp(-|x|)) so softplus(+-x) = max(+-x,0) + sp_out
__device__ __forceinline__ float sig_sp(float x, float& sp_out) {
    float e = __expf(-fabsf(x));
    float d = 1.0f + e;
    sp_out = __logf(d);
    float r = __builtin_amdgcn_rcpf(d);
    return (x >= 0.0f) ? r : e * r;
}

struct Arr10 { float v[10]; };  // cols j0-1 .. j0+8 (halos via wave shuffle)

__device__ __forceinline__ void load8(const float* p, float* o) {
    const float4 a = *(const float4*)p;
    const float4 b = *(const float4*)(p + 4);
    o[0]=a.x; o[1]=a.y; o[2]=a.z; o[3]=a.w;
    o[4]=b.x; o[5]=b.y; o[6]=b.z; o[7]=b.w;
}

__device__ __forceinline__ void zero8(float* o) {
#pragma unroll
    for (int k = 0; k < 8; ++k) o[k] = 0.f;
}

__device__ __forceinline__ Arr10 strip10_from(const float* x, int lane) {
    Arr10 r;
    float l = __shfl_up(x[7], 1, 64);
    float h = __shfl_down(x[0], 1, 64);
    r.v[0] = (lane == 0)  ? 0.f : l;    // image-left boundary
    r.v[9] = (lane == 63) ? 0.f : h;    // image-right boundary
#pragma unroll
    for (int k = 0; k < 8; ++k) r.v[k + 1] = x[k];
    return r;
}

__global__ __launch_bounds__(256) void connect_loss_main(
        const float* __restrict__ pred,   // (B, 8, H, W)
        const float* __restrict__ tgt,    // (B, 1, H, W)
        float* __restrict__ partials,     // mode 1: [6][NBLK]
        double* __restrict__ wsd,         // mode 0: 27 doubles
        int mode)
{
    const int b    = blockIdx.y;
    const int tid  = threadIdx.x;
    const int lane = tid & 63;
    const int wv   = tid >> 6;
    const int i    = blockIdx.x * ROWS_PER_BLOCK + wv;  // wave == one row
    const int j0   = lane << 3;
    const int p0   = i * WDIM + j0;
    const bool rm  = (i > 0), rp = (i < HDIM - 1);
    const bool l0  = (lane == 0), l63 = (lane == 63);

    const float* tb = tgt  + (size_t)b * HW;
    const float* pb = pred + (size_t)b * 8 * HW;

    // ---------- issue ALL early loads first: target rows + sections 0,1 ----
    // Section s pairs channels (s, 7-s). Ra = ch(7-s) @ row i-1 (for vote of
    // d_s); Rb = ch(s) @ row i+1 (for vote of d_{7-s}).
    float t0[8], t1[8], t2[8];
    zero8(t0); zero8(t2);
    if (rm) load8(tb + p0 - WDIM, t0);
    load8(tb + p0, t1);
    if (rp) load8(tb + p0 + WDIM, t2);

    float Axa[8], Axb[8], Ara[8], Arb[8];
    float Bxa[8], Bxb[8], Bra[8], Brb[8];

    auto pload = [&](int cA, int cB, float* Xa, float* Xb, float* Ra, float* Rb) {
        load8(pb + (size_t)cA * HW + p0, Xa);
        load8(pb + (size_t)cB * HW + p0, Xb);
        if (rm) load8(pb + (size_t)cB * HW + p0 - WDIM, Ra); else zero8(Ra);
        if (rp) load8(pb + (size_t)cA * HW + p0 + WDIM, Rb); else zero8(Rb);
    };
    pload(0, 7, Axa, Axb, Ara, Arb);        // section 0
    pload(1, 6, Bxa, Bxb, Bra, Brb);        // section 1 (prefetch)

    // ---------- target strips + conn/edge bits (covers pred load latency) --
    Arr10 tm = strip10_from(t0, lane);
    Arr10 tc = strip10_from(t1, lane);
    Arr10 tp = strip10_from(t2, lane);

    int mb[8];
#pragma unroll
    for (int k = 0; k < 8; ++k) {
        const float t_ = tc.v[k + 1];
        const float s8 = tm.v[k] + tm.v[k+1] + tm.v[k+2]
                       + tc.v[k] + tc.v[k+2]
                       + tp.v[k] + tp.v[k+1] + tp.v[k+2];
        const float sc = t_ * s8;
        int bits = (sc < 8.0f && sc > 0.0f) ? 256 : 0;
        if (t_ > 0.5f) {
            bits |= (tm.v[k]   > 0.5f ?   1 : 0);
            bits |= (tm.v[k+1] > 0.5f ?   2 : 0);
            bits |= (tm.v[k+2] > 0.5f ?   4 : 0);
            bits |= (tc.v[k]   > 0.5f ?   8 : 0);
            bits |= (tc.v[k+2] > 0.5f ?  16 : 0);
            bits |= (tp.v[k]   > 0.5f ?  32 : 0);
            bits |= (tp.v[k+1] > 0.5f ?  64 : 0);
            bits |= (tp.v[k+2] > 0.5f ? 128 : 0);
        }
        mb[k] = bits;
    }

    float fp[8], xmin[8], bce0 = 0.f, bce1 = 0.f;
#pragma unroll
    for (int k = 0; k < 8; ++k) { fp[k] = 0.f; xmin[k] = 1e30f; }

    // own-channel math: sigmoid + BCE (logit-space softplus, XOR-sign select)
    // bit c of mb[k] set -> target=1 -> loss = softplus(-x); else softplus(x).
    auto own_ch = [&](int c, const float* x, float* s, float& acc) {
#pragma unroll
        for (int k = 0; k < 8; ++k) {
            float sp;
            const float sv = sig_sp(x[k], sp);
            s[k] = sv;
            xmin[k] = fminf(xmin[k], x[k]);
            const int sbit = (mb[k] << (31 - c)) & 0x80000000;
            const float sel = __int_as_float(__float_as_int(x[k]) ^ sbit);
            acc += fminf(fmaxf(sel, 0.f) + sp, 100.f);
        }
    };
    // vote: fp[k] = max(fp[k], s[k] * sigmoid(neigh)); off 0/1/2 = col -1/0/+1
    auto vote = [&](const float* s, const Arr10& n, int off, bool rv) {
#pragma unroll
        for (int k = 0; k < 8; ++k) {
            bool ok = rv;
            if (off == 0 && k == 0) ok = ok && !l0;
            if (off == 2 && k == 7) ok = ok && !l63;
            const float q = ok ? fast_sig(n.v[k + off]) : 0.f;
            fp[k] = fmaxf(fp[k], s[k] * q);
        }
    };
    auto section = [&](int cA, int cB, const float* Xa, const float* Xb,
                       const float* Ra, const float* Rb,
                       int offA, int offB, bool gA, bool gB) {
        Arr10 nA = strip10_from(Ra, lane);
        Arr10 nB = strip10_from(Rb, lane);
        float s_a[8], s_b[8];
        own_ch(cA, Xa, s_a, bce0);
        own_ch(cB, Xb, s_b, bce1);
        vote(s_a, nA, offA, gA);
        vote(s_b, nB, offB, gB);
    };

    // ---------- pipelined sections: compute s while s+1 loads are in flight
    section(0, 7, Axa, Axb, Ara, Arb, 0, 2, rm, rp);
    pload(2, 5, Axa, Axb, Ara, Arb);        // section 2 (prefetch into A)
    section(1, 6, Bxa, Bxb, Bra, Brb, 1, 1, rm, rp);
    load8(pb + 3 * (size_t)HW + p0, Bxa);   // section 3: in-row pair (3,4)
    load8(pb + 4 * (size_t)HW + p0, Bxb);
    section(2, 5, Axa, Axb, Ara, Arb, 2, 0, rm, rp);
    section(3, 4, Bxa, Bxb, Bxb, Bxa, 0, 2, true, true);

    // ---------- epilogue: edge loss + dice partials ----------
    float e_num = 0.f, e_den = 0.f, inter = 0.f, fpsum = 0.f, tsum = 0.f;
#pragma unroll
    for (int k = 0; k < 8; ++k) {
        const float ef = (mb[k] & 256) ? 1.f : 0.f;
        const float m  = xmin[k];
        const float t_ = tc.v[k + 1];
        float sp;
        const float pmin = sig_sp(m, sp);           // sigmoid monotone
        e_num += ef * fminf(fmaxf(m, 0.f) + sp, 100.f);  // softplus(xmin)
        e_den += ef * pmin;
        inter += fp[k] * t_;
        fpsum += fp[k];
        tsum  += t_;
    }

    // ---------- block reduction of 6 partials ----------
    float vals[6] = {bce0 + bce1, e_num, e_den, inter, fpsum, tsum};
    __shared__ float red[4][6];
#pragma unroll
    for (int k = 0; k < 6; ++k) {
        float v = vals[k];
#pragma unroll
        for (int o = 32; o > 0; o >>= 1) v += __shfl_down(v, o, 64);
        if (lane == 0) red[wv][k] = v;
    }
    __syncthreads();
    if (tid < 6) {
        const int k = tid;
        const float sum = red[0][k] + red[1][k] + red[2][k] + red[3][k];
        if (mode == 1) {
            partials[k * NBLK + b * NBLKX + blockIdx.x] = sum;
        } else {
            double* dst;
            switch (k) {
                case 0:  dst = wsd + 0;       break;
                case 1:  dst = wsd + 1;       break;
                case 2:  dst = wsd + 2;       break;
                case 3:  dst = wsd + 3 + b;   break;
                case 4:  dst = wsd + 11 + b;  break;
                default: dst = wsd + 19 + b;  break;
            }
            atomicAdd(dst, (double)sum);
        }
    }
}

__global__ __launch_bounds__(256) void connect_loss_final(
        const float* __restrict__ partials,
        const double* __restrict__ wsd,
        float* __restrict__ out, int mode)
{
    __shared__ double red4[4];
    __shared__ double gsum[3];
    __shared__ double bsum[3][BATCH];
    const int t = threadIdx.x;

    if (mode == 1) {
        const int lane = t & 63, wid = t >> 6;
        {   // per-batch categories (k=3,4,5): 8 groups of 32 lanes
            const int g = t >> 5, e = t & 31;
#pragma unroll
            for (int k = 3; k < 6; ++k) {
                double v = 0.0;
                for (int m = e; m < NBLKX; m += 32)
                    v += (double)partials[k * NBLK + g * NBLKX + m];
                for (int o = 16; o > 0; o >>= 1) v += __shfl_down(v, o, 32);
                if (e == 0) bsum[k - 3][g] = v;
            }
        }
        for (int k = 0; k < 3; ++k) {   // global categories
            double v = 0.0;
            for (int idx = t; idx < NBLK; idx += 256)
                v += (double)partials[k * NBLK + idx];
            for (int o = 32; o > 0; o >>= 1) v += __shfl_down(v, o, 64);
            if (lane == 0) red4[wid] = v;
            __syncthreads();
            if (t == 0) gsum[k] = red4[0] + red4[1] + red4[2] + red4[3];
            __syncthreads();
        }
        if (t == 0) {
            const double conn_loss = gsum[0] / (double)((size_t)BATCH * 8 * HW);
            const double edge_loss = gsum[1] / gsum[2];
            double seg = 0.0;
            for (int bb = 0; bb < BATCH; ++bb) {
                const double dice = (2.0 * bsum[0][bb] + 1.0)
                                  / (bsum[1][bb] + bsum[2][bb] + 1.0);
                seg += 1.0 - dice;
            }
            out[0] = (float)(conn_loss + edge_loss + seg / (double)BATCH);
        }
    } else if (t == 0) {
        const double conn_loss = wsd[0] / (double)((size_t)BATCH * 8 * HW);
        const double edge_loss = wsd[1] / wsd[2];
        double seg = 0.0;
        for (int bb = 0; bb < BATCH; ++bb) {
            const double dice = (2.0 * wsd[3 + bb] + 1.0)
                              / (wsd[11 + bb] + wsd[19 + bb] + 1.0);
            seg += 1.0 - dice;
        }
        out[0] = (float)(conn_loss + edge_loss + seg / (double)BATCH);
    }
}

extern "C" void kernel_launch(void* const* d_in, const int* in_sizes, int n_in,
                              void* d_out, int out_size, void* d_ws, size_t ws_size,
                              hipStream_t stream)
{
    const float* pred = (const float*)d_in[0];   // (8, 8, 512, 512)
    const float* tgt  = (const float*)d_in[1];   // (8, 1, 512, 512)
    // d_in[2]/d_in[3] (hori/verti) are exact one-pixel shift permutation
    // matrices -> implemented as index shifts (verified earlier, absmax 0).

    const dim3 grid(NBLKX, BATCH);
    const size_t needA = (size_t)6 * NBLK * sizeof(float);

    if (ws_size >= needA) {
        float* partials = (float*)d_ws;
        connect_loss_main<<<grid, 256, 0, stream>>>(pred, tgt, partials, nullptr, 1);
        connect_loss_final<<<1, 256, 0, stream>>>(partials, nullptr, (float*)d_out, 1);
    } else {
        double* wsd = (double*)d_ws;
        hipMemsetAsync(d_ws, 0, 27 * sizeof(double), stream);
        connect_loss_main<<<grid, 256, 0, stream>>>(pred, tgt, nullptr, wsd, 0);
        connect_loss_final<<<1, 1, 0, stream>>>(nullptr, wsd, (float*)d_out, 0);
    }
}